// Round 8
// baseline (4419.993 us; speedup 1.0000x reference)
//
#include <hip/hip_runtime.h>

// ---------------------------------------------------------------------------
// Encoder_conv: emb (1x1 conv) -> 3x { multi-tap K=2 convs summed -> LSTM scan
// with per-step attention gating }.
// B=32, W=512, H=256, 4H=1024, NINP=128, K=2, NLAYERS=3.
//
// Round 13: R11 base (rec 1062us best: DPP main butterfly, hx 72-elem
// swizzle, 192 VGPR + 64 LDS weight dw/thread). R12's raw-asm permlane leg
// produced wrong attn data (no compiler hazard padding around opaque asm;
// builtins only from now on). New attn tail, proven mechanics only:
//  - in-wave reduce stops at 16-lane rows: legs 8 (row_ror:8 DPP builtin;
//    rot8 == xor8 within 16), 4 (shfl), 2,1 (quad_perm DPP, R11-proven).
//    Pre-barrier tail: 6 serial DS shfls -> 1 shfl + 3 DPP.
//  - each wave writes 4 row partials -> red[2][32]; the cross-row sum (8x
//    float4 broadcast LDS reads + fixed-order adds) moves to next step's
//    loop top where ~1000 cyc of dot slack hides it. m_ identical on all
//    threads (same code/order). Attn bracketing change = reassociation-level
//    (~1e-7) only.
// ---------------------------------------------------------------------------

typedef _Float16 h2 __attribute__((ext_vector_type(2)));

static __device__ __forceinline__ float fdot2(unsigned a, unsigned b, float c) {
#if __has_builtin(__builtin_amdgcn_fdot2)
  return __builtin_amdgcn_fdot2(__builtin_bit_cast(h2, a),
                                __builtin_bit_cast(h2, b), c, false);
#else
  h2 x = __builtin_bit_cast(h2, a), y = __builtin_bit_cast(h2, b);
  return c + (float)x[0] * (float)y[0] + (float)x[1] * (float)y[1];
#endif
}

static __device__ __forceinline__ unsigned short f16b(float v) {
  _Float16 h = (_Float16)v;
  return __builtin_bit_cast(unsigned short, h);
}

static __device__ __forceinline__ float sigm(float x) {
  return 1.0f / (1.0f + __expf(-x));
}
static __device__ __forceinline__ float tanh_(float x) {
  return 1.0f - 2.0f / (1.0f + __expf(2.0f * x));
}

// x + (x from a DPP-reachable lane permutation), via the mov_dpp BUILTIN
// (compiler inserts required hazard waits — raw asm does not, r12 lesson).
// CTRLs: quad_perm xor1 = 0xB1 ; quad_perm xor2 = 0x4E ;
// row_ror:8 = 0x128 (rotate-by-8 within a 16-lane row == xor 8, exact).
template <int CTRL>
static __device__ __forceinline__ float dpp_xadd(float x) {
  int y = __builtin_amdgcn_mov_dpp(__builtin_bit_cast(int, x), CTRL, 0xF, 0xF,
                                   true);
  return x + __builtin_bit_cast(float, y);
}

// Packs rec_w per layer (131072 dwords/layer) for the butterfly rec kernel.
// Thread tid: s=tid&3, u=tid>>2; rows row=(rl>>1)*256+(rl&1)*128+u (rl=0..7);
// K-pairs j in [0,32) at global pair cp = s*32+j:
//   j<24      -> VGPR: off = (rl*24+j)*512 + tid
//   j=24..31  -> LDS : c = rl*2+((j-24)>>2), k=(j-24)&3
//                      off = 98304 + c*2048 + tid*4 + k
__global__ __launch_bounds__(256) void prep_rw(const float* __restrict__ rw,
                                               unsigned* __restrict__ rwp) {
  int idx = blockIdx.x * 256 + threadIdx.x;
  if (idx >= 3 * 131072) return;
  int l = idx / 131072, pos = idx % 131072;
  int tid, rl, j;
  if (pos < 98304) {
    int d = pos >> 9;
    tid = pos & 511;
    rl = d / 24;
    j = d % 24;
  } else {
    int p = pos - 98304;
    int c = p >> 11, rem = p & 2047;
    tid = rem >> 2;
    int k = rem & 3;
    rl = c >> 1;
    j = 24 + (c & 1) * 4 + k;
  }
  int s = tid & 3, u = tid >> 2;
  int row = (rl >> 1) * 256 + (rl & 1) * 128 + u;
  int cp = s * 32 + j;
  const float* src = rw + (l * 1024 + row) * 256 + 2 * cp;
  rwp[idx] = (unsigned)f16b(src[0]) | ((unsigned)f16b(src[1]) << 16);
}

// cwp[jj][o][k][d] = pack(f16(conv_w[jj][o][2d][k]), f16(conv_w[jj][o][2d+1][k]))
__global__ __launch_bounds__(256) void prep_cw(const float* __restrict__ cw,
                                               unsigned* __restrict__ cwp) {
  int idx = blockIdx.x * 256 + threadIdx.x;
  if (idx >= 6 * 1024 * 2 * 128) return;
  int d = idx & 127, k = (idx >> 7) & 1, o = (idx >> 8) & 1023, jj = idx >> 18;
  const float* src = cw + ((jj * 1024 + o) * 256 + 2 * d) * 2 + k;
  unsigned v = (unsigned)f16b(src[0]) | ((unsigned)f16b(src[2]) << 16);
  cwp[idx] = v;
}

// x0[b,w,h] = sum_c emb_w[h,c]*input[b,c,w] + emb_b[h]; store f16 + out tail.
__global__ __launch_bounds__(256) void emb_kernel(
    const float* __restrict__ inp, const float* __restrict__ ew,
    const float* __restrict__ eb, unsigned short* __restrict__ x0f,
    float* __restrict__ out) {
  __shared__ float xt[32][65];
  __shared__ float wt[64][33];
  int b = blockIdx.z, w0 = blockIdx.x * 64, h0 = blockIdx.y * 64;
  int tid = threadIdx.x, tx = tid & 15, ty = tid >> 4;
  float acc[4][4] = {};
  for (int c0 = 0; c0 < 128; c0 += 32) {
    __syncthreads();
#pragma unroll
    for (int i = 0; i < 8; i++) {
      int f = i * 256 + tid, c = f >> 6, wl = f & 63;
      xt[c][wl] = inp[(b * 128 + c0 + c) * 512 + w0 + wl];
    }
#pragma unroll
    for (int i = 0; i < 8; i++) {
      int f = i * 256 + tid, h = f >> 5, c = f & 31;
      wt[h][c] = ew[(h0 + h) * 128 + c0 + c];
    }
    __syncthreads();
#pragma unroll
    for (int c = 0; c < 32; c++) {
      float xv[4], wv[4];
#pragma unroll
      for (int q = 0; q < 4; q++) xv[q] = xt[c][ty * 4 + q];
#pragma unroll
      for (int p = 0; p < 4; p++) wv[p] = wt[tx * 4 + p][c];
#pragma unroll
      for (int q = 0; q < 4; q++)
#pragma unroll
        for (int p = 0; p < 4; p++) acc[q][p] += xv[q] * wv[p];
    }
  }
#pragma unroll
  for (int q = 0; q < 4; q++) {
    int w = w0 + ty * 4 + q;
#pragma unroll
    for (int p = 0; p < 4; p++) {
      int h = h0 + tx * 4 + p;
      float v = acc[q][p] + eb[h];
      x0f[(b * 512 + w) * 256 + h] = f16b(v);
      if (w >= 510) out[(b * 256 + h) * 2 + (w - 510)] = v;  // x[0] tail
    }
  }
}

// ig[b,w,o] = sum_j sum_{i,k} xpad_j[b,w-1+k,i] * cw[off+j][o,i,k] + biases
__global__ __launch_bounds__(256) void conv_kernel(
    const unsigned short* __restrict__ xf, const unsigned* __restrict__ cwp,
    const float* __restrict__ cb, const float* __restrict__ hidden,
    unsigned short* __restrict__ igf, int l, int off) {
  __shared__ __align__(16) unsigned xs[65][20];    // [pad-col][dw16], stride 20
  __shared__ __align__(16) unsigned wsm[2][16][66];// [k][dw16][o], pad 66
  int b = blockIdx.z, w0 = blockIdx.x * 64, o0 = blockIdx.y * 64;
  int tid = threadIdx.x, tx = tid & 15, ty = tid >> 4;
  float acc[4][4] = {};
  int nl = l + 1;
  for (int j = 0; j < nl; j++) {
    const unsigned* xj = (const unsigned*)(xf + j * 4194304 + b * 512 * 256);
    const unsigned* cwj = cwp + (off + j) * 262144;
    for (int c0 = 0; c0 < 256; c0 += 32) {
      int d0 = c0 >> 1;
      __syncthreads();
#pragma unroll
      for (int i = 0; i < 5; i++) {
        int f = i * 256 + tid;
        if (f < 1040) {
          int col = f >> 4, dw = f & 15;
          int w = w0 - 1 + col;
          unsigned v;
          if (w >= 0) {
            v = xj[w * 128 + d0 + dw];
          } else {  // left pad: hidden[j][b][i][1]
            const float* hp = hidden + ((j * 32 + b) * 256 + 2 * (d0 + dw)) * 2 + 1;
            v = (unsigned)f16b(hp[0]) | ((unsigned)f16b(hp[2]) << 16);
          }
          xs[col][dw] = v;
        }
      }
#pragma unroll
      for (int i = 0; i < 8; i++) {
        int f = i * 256 + tid;
        int oo = f >> 5, k = (f >> 4) & 1, dw = f & 15;
        wsm[k][dw][oo] = cwj[(o0 + oo) * 256 + k * 128 + d0 + dw];
      }
      __syncthreads();
#pragma unroll
      for (int g = 0; g < 4; g++) {
        uint4 xv[5];
#pragma unroll
        for (int q = 0; q < 5; q++)
          xv[q] = *(const uint4*)&xs[ty * 4 + q][g * 4];
#pragma unroll
        for (int p = 0; p < 4; p++) {
          unsigned wv0[4], wv1[4];
#pragma unroll
          for (int r = 0; r < 4; r++) {
            wv0[r] = wsm[0][g * 4 + r][tx * 4 + p];
            wv1[r] = wsm[1][g * 4 + r][tx * 4 + p];
          }
#pragma unroll
          for (int q = 0; q < 4; q++) {
            float a = acc[q][p];
            a = fdot2(wv0[0], xv[q].x, a);
            a = fdot2(wv0[1], xv[q].y, a);
            a = fdot2(wv0[2], xv[q].z, a);
            a = fdot2(wv0[3], xv[q].w, a);
            a = fdot2(wv1[0], xv[q + 1].x, a);
            a = fdot2(wv1[1], xv[q + 1].y, a);
            a = fdot2(wv1[2], xv[q + 1].z, a);
            a = fdot2(wv1[3], xv[q + 1].w, a);
            acc[q][p] = a;
          }
        }
      }
    }
  }
#pragma unroll
  for (int p = 0; p < 4; p++) {
    int o = o0 + tx * 4 + p;
    float bias = 0.f;
    for (int j = 0; j < nl; j++) bias += cb[(off + j) * 1024 + o];
#pragma unroll
    for (int q = 0; q < 4; q++) {
      int w = w0 + ty * 4 + q;
      igf[(b * 512 + w) * 1024 + o] = f16b(acc[q][p] + bias);
    }
  }
}

// One WG per batch; 512 threads; lane (s=tid&3, u=tid>>2) computes 8 partial
// row-dots over 1/4 of hx, butterfly-reduced via DPP quad_perm adds.
// 1 barrier/step. Weights: 192 dw/thread pinned VGPRs + 64 dw/thread LDS.
__global__ __launch_bounds__(512)
__attribute__((amdgpu_waves_per_eu(2, 2)))
void rec_kernel(const _Float16* __restrict__ igf, const unsigned* __restrict__ rwp_l,
                const float* __restrict__ rb, const float* __restrict__ aw,
                const float* __restrict__ hidden, const float* __restrict__ context,
                int l, unsigned short* __restrict__ xnext, float* __restrict__ out) {
  __shared__ __align__(16) uint4 w_lds4[16 * 512];          // 128 KB
  // quarter s at elem offset s*72 (144B) -> each quarter on its own bank quad
  __shared__ __align__(16) unsigned short hx_buf[2][288];
  // 4 row-partials per wave (16-lane-row sums), double-buffered
  __shared__ __align__(16) float red[2][32];
  int b = blockIdx.x, tid = threadIdx.x;
  int s = tid & 3, u = tid >> 2, lane = tid & 63, wid = tid >> 6;
  int hh = s & 1;
  int u2 = u + 128 * hh;                 // this lane's unit
  int hxi = (u2 >> 6) * 72 + (u2 & 63);  // swizzled store index for u2

  // 192 weight dwords -> pinned VGPRs
  unsigned wv[192];
#pragma unroll
  for (int d = 0; d < 192; d++) wv[d] = rwp_l[d * 512 + tid];
#pragma unroll
  for (int d = 0; d < 192; d++) asm volatile("" : "+v"(wv[d]));

  // 64 weight dwords -> LDS (conflict-free b128)
  {
    const uint4* g16 = (const uint4*)(rwp_l + 98304);
#pragma unroll
    for (int c = 0; c < 16; c++) w_lds4[c * 512 + tid] = g16[c * 512 + tid];
  }

  float rb0 = rb[u2], rb1 = rb[256 + u2], rb2 = rb[512 + u2], rb3 = rb[768 + u2];
  float awj = aw[u2];
  float cx = context[((l * 32 + b) * 256 + u2) * 2 + 1];
  if (tid < 256)
    hx_buf[1][(tid >> 6) * 72 + (tid & 63)] =
        f16b(hidden[(((l + 1) * 32 + b) * 256 + tid) * 2 + 1]);
  float h_prev = 0.f;
  __syncthreads();

  const _Float16* igb = igf + (b * 512) * 1024 + u2;

  for (int t = 0; t < 512; t++) {
    int cur = t & 1, prv = cur ^ 1;
    // ig prefetch (consumed after butterfly, ~1000 cyc later)
    const _Float16* ip = igb + t * 1024;
    float ig0 = (float)ip[0], ig1 = (float)ip[256];
    float ig2 = (float)ip[512], ig3 = (float)ip[768];
    // m = a_(t-1): cross-row sum of 32 partials, hidden under the dot phase.
    // Same code/order on every thread -> identical m_ everywhere.
    float m_ = 1.0f;
    if (t) {
      const float4* rp = (const float4*)red[prv];
      float a8[8];
#pragma unroll
      for (int i = 0; i < 8; i++) {
        float4 r = rp[i];
        a8[i] = (r.x + r.y) + (r.z + r.w);
      }
      m_ = sigm((((a8[0] + a8[1]) + (a8[2] + a8[3])) +
                 ((a8[4] + a8[5]) + (a8[6] + a8[7]))));
    }

    float acc[8] = {};
    const uint4* hq = (const uint4*)(&hx_buf[prv][s * 72]);
#pragma unroll
    for (int q = 0; q < 6; q++) {
      uint4 h = hq[q];
#pragma unroll
      for (int rl = 0; rl < 8; rl++) {
        acc[rl] = fdot2(wv[rl * 24 + q * 4 + 0], h.x, acc[rl]);
        acc[rl] = fdot2(wv[rl * 24 + q * 4 + 1], h.y, acc[rl]);
        acc[rl] = fdot2(wv[rl * 24 + q * 4 + 2], h.z, acc[rl]);
        acc[rl] = fdot2(wv[rl * 24 + q * 4 + 3], h.w, acc[rl]);
      }
    }
#pragma unroll
    for (int q = 6; q < 8; q++) {
      uint4 h = hq[q];
#pragma unroll
      for (int rl = 0; rl < 8; rl++) {
        uint4 lw = w_lds4[(rl * 2 + (q - 6)) * 512 + tid];
        acc[rl] = fdot2(lw.x, h.x, acc[rl]);
        acc[rl] = fdot2(lw.y, h.y, acc[rl]);
        acc[rl] = fdot2(lw.z, h.z, acc[rl]);
        acc[rl] = fdot2(lw.w, h.w, acc[rl]);
      }
    }
    // butterfly over s (xor 1, then 2) via DPP quad_perm adds (VALU pipe).
    // Same pair/group order as shfl version -> bit-identical sums.
#pragma unroll
    for (int rl = 0; rl < 8; rl++) acc[rl] = dpp_xadd<0xB1>(acc[rl]);
#pragma unroll
    for (int rl = 0; rl < 8; rl++) acc[rl] = dpp_xadd<0x4E>(acc[rl]);

    // this lane's 4 gates (rows g*256 + u2 <-> acc[g*2+hh])
    float di = hh ? acc[1] : acc[0];
    float df = hh ? acc[3] : acc[2];
    float dc = hh ? acc[5] : acc[4];
    float do_ = hh ? acc[7] : acc[6];
    float g_i = ig0 + rb0 + m_ * di;
    float g_f = ig1 + rb1 + m_ * df;
    float g_c = ig2 + rb2 + m_ * dc;
    float g_o = ig3 + rb3 + m_ * do_;
    cx = sigm(g_f) * cx + sigm(g_i) * tanh_(g_c);
    float h_raw = sigm(g_o) * tanh_(cx);

    // attention partial (mask the s=2,3 duplicate copies), reduced only to
    // 16-lane-row level: legs 8 (row_ror:8), 4 (shfl), 2,1 (quad_perm).
    // One DS op on the tail instead of six.
    float part = (s < 2) ? h_raw * awj : 0.f;
    part = dpp_xadd<0x128>(part);   // xor 8
    part += __shfl_xor(part, 4);    // xor 4
    part = dpp_xadd<0x4E>(part);    // xor 2
    part = dpp_xadd<0xB1>(part);    // xor 1
    if ((lane & 15) == 0) red[cur][wid * 4 + (lane >> 4)] = part;

    if (s < 2) {
      hx_buf[cur][hxi] = f16b(h_raw);  // store RAW h; gating deferred
      if (t) {
        float hg = h_prev * m_;  // gated h of step t-1
        xnext[(b * 512 + (t - 1)) * 256 + u2] = f16b(hg);
        if (t == 511)
          out[(((l + 1) * 32 + b) * 256 + u2) * 2 + 0] = hg;  // x tail w=510
      }
      if (t >= 510)
        out[65536 + ((l * 32 + b) * 256 + u2) * 2 + (t - 510)] = cx;  // nc tail
    }
    if (tid == 0 && t) out[114688 + (l * 32 + b) * 511 + (t - 1)] = m_;  // attn
    h_prev = h_raw;
    __syncthreads();
  }
  // flush last step (ungated)
  if (s < 2) {
    xnext[(b * 512 + 511) * 256 + u2] = f16b(h_prev);
    out[(((l + 1) * 32 + b) * 256 + u2) * 2 + 1] = h_prev;  // x tail w=511
  }
}

extern "C" void kernel_launch(void* const* d_in, const int* in_sizes, int n_in,
                              void* d_out, int out_size, void* d_ws,
                              size_t ws_size, hipStream_t stream) {
  const float* input  = (const float*)d_in[0];
  const float* hidden = (const float*)d_in[1];
  const float* context= (const float*)d_in[2];
  const float* emb_w  = (const float*)d_in[3];
  const float* emb_b  = (const float*)d_in[4];
  const float* conv_w = (const float*)d_in[5];
  const float* conv_b = (const float*)d_in[6];
  const float* rec_w  = (const float*)d_in[7];
  const float* rec_b  = (const float*)d_in[8];
  const float* attn_w = (const float*)d_in[9];
  float* out = (float*)d_out;

  char* ws = (char*)d_ws;
  unsigned short* xf16 = (unsigned short*)ws;                    // 4 x 4,194,304 f16 = 32 MB
  _Float16* igf = (_Float16*)(ws + 33554432);                    // 16,777,216 f16 = 32 MB
  unsigned* rwp = (unsigned*)(ws + 67108864);                    // 1.5 MB
  unsigned* cwp = (unsigned*)(ws + 68681728);                    // 6 MB

  hipLaunchKernelGGL(prep_rw, dim3(1536), dim3(256), 0, stream, rec_w, rwp);
  hipLaunchKernelGGL(prep_cw, dim3(6144), dim3(256), 0, stream, conv_w, cwp);
  hipLaunchKernelGGL(emb_kernel, dim3(8, 4, 32), dim3(256), 0, stream,
                     input, emb_w, emb_b, xf16, out);
  int off = 0;
  for (int l = 0; l < 3; l++) {
    hipLaunchKernelGGL(conv_kernel, dim3(8, 16, 32), dim3(256), 0, stream,
                       xf16, cwp, conv_b, hidden, (unsigned short*)igf, l, off);
    hipLaunchKernelGGL(rec_kernel, dim3(32), dim3(512), 0, stream,
                       igf, rwp + l * 131072, rec_b + l * 1024,
                       attn_w + l * 256, hidden, context, l,
                       xf16 + (l + 1) * 4194304, out);
    off += l + 1;
  }
}

// Round 12
// 4255.432 us; speedup vs baseline: 1.0387x; 1.0387x over previous
//
#include <hip/hip_runtime.h>

// ---------------------------------------------------------------------------
// Encoder_conv: emb (1x1 conv) -> 3x { multi-tap K=2 convs summed -> LSTM scan
// with per-step attention gating }.
// B=32, W=512, H=256, 4H=1024, NINP=128, K=2, NLAYERS=3.
//
// Round 17: restore R11 verbatim — the session's best VERIFIED kernel
// (total 4215us; rec 1062us/dispatch; absmax 0.00390625). The conv/rec
// overlap line (R14-R16) is abandoned: one staging bug (NaN), then two
// container failures on byte-identical source — kernel-correlated,
// undiagnosable without logs; prime suspect is the fused kernel's
// 192-pinned-asm-VGPR + inlined conv body + waves_per_eu(2,2) combination.
// R11's content: R9 base (192 VGPR + 64 LDS weight dw/thread, hx_buf
// 72-elem quarter swizzle -> 0 bank conflicts) with the main butterfly
// (xor1/xor2 over s) as DPP quad_perm adds instead of 16 ds_bpermute
// (isolated win: rec 1134 -> 1062us). Attn reduce keeps the original
// 6-leg shfl chain (R12 raw-asm permlane: wrong results; R13 cross-row
// restructure: +66us — both reverted).
// ---------------------------------------------------------------------------

typedef _Float16 h2 __attribute__((ext_vector_type(2)));

static __device__ __forceinline__ float fdot2(unsigned a, unsigned b, float c) {
#if __has_builtin(__builtin_amdgcn_fdot2)
  return __builtin_amdgcn_fdot2(__builtin_bit_cast(h2, a),
                                __builtin_bit_cast(h2, b), c, false);
#else
  h2 x = __builtin_bit_cast(h2, a), y = __builtin_bit_cast(h2, b);
  return c + (float)x[0] * (float)y[0] + (float)x[1] * (float)y[1];
#endif
}

static __device__ __forceinline__ unsigned short f16b(float v) {
  _Float16 h = (_Float16)v;
  return __builtin_bit_cast(unsigned short, h);
}

static __device__ __forceinline__ float sigm(float x) {
  return 1.0f / (1.0f + __expf(-x));
}
static __device__ __forceinline__ float tanh_(float x) {
  return 1.0f - 2.0f / (1.0f + __expf(2.0f * x));
}

// x + (x from lane^delta) within each quad, via DPP quad_perm.
// xor1 = quad_perm(1,0,3,2) = 0xB1 ; xor2 = quad_perm(2,3,0,1) = 0x4E.
template <int CTRL>
static __device__ __forceinline__ float dpp_xadd(float x) {
  int y = __builtin_amdgcn_mov_dpp(__builtin_bit_cast(int, x), CTRL, 0xF, 0xF,
                                   true);
  return x + __builtin_bit_cast(float, y);
}

// Packs rec_w per layer (131072 dwords/layer) for the butterfly rec kernel.
// Thread tid: s=tid&3, u=tid>>2; rows row=(rl>>1)*256+(rl&1)*128+u (rl=0..7);
// K-pairs j in [0,32) at global pair cp = s*32+j:
//   j<24      -> VGPR: off = (rl*24+j)*512 + tid
//   j=24..31  -> LDS : c = rl*2+((j-24)>>2), k=(j-24)&3
//                      off = 98304 + c*2048 + tid*4 + k
__global__ __launch_bounds__(256) void prep_rw(const float* __restrict__ rw,
                                               unsigned* __restrict__ rwp) {
  int idx = blockIdx.x * 256 + threadIdx.x;
  if (idx >= 3 * 131072) return;
  int l = idx / 131072, pos = idx % 131072;
  int tid, rl, j;
  if (pos < 98304) {
    int d = pos >> 9;
    tid = pos & 511;
    rl = d / 24;
    j = d % 24;
  } else {
    int p = pos - 98304;
    int c = p >> 11, rem = p & 2047;
    tid = rem >> 2;
    int k = rem & 3;
    rl = c >> 1;
    j = 24 + (c & 1) * 4 + k;
  }
  int s = tid & 3, u = tid >> 2;
  int row = (rl >> 1) * 256 + (rl & 1) * 128 + u;
  int cp = s * 32 + j;
  const float* src = rw + (l * 1024 + row) * 256 + 2 * cp;
  rwp[idx] = (unsigned)f16b(src[0]) | ((unsigned)f16b(src[1]) << 16);
}

// cwp[jj][o][k][d] = pack(f16(conv_w[jj][o][2d][k]), f16(conv_w[jj][o][2d+1][k]))
__global__ __launch_bounds__(256) void prep_cw(const float* __restrict__ cw,
                                               unsigned* __restrict__ cwp) {
  int idx = blockIdx.x * 256 + threadIdx.x;
  if (idx >= 6 * 1024 * 2 * 128) return;
  int d = idx & 127, k = (idx >> 7) & 1, o = (idx >> 8) & 1023, jj = idx >> 18;
  const float* src = cw + ((jj * 1024 + o) * 256 + 2 * d) * 2 + k;
  unsigned v = (unsigned)f16b(src[0]) | ((unsigned)f16b(src[2]) << 16);
  cwp[idx] = v;
}

// x0[b,w,h] = sum_c emb_w[h,c]*input[b,c,w] + emb_b[h]; store f16 + out tail.
__global__ __launch_bounds__(256) void emb_kernel(
    const float* __restrict__ inp, const float* __restrict__ ew,
    const float* __restrict__ eb, unsigned short* __restrict__ x0f,
    float* __restrict__ out) {
  __shared__ float xt[32][65];
  __shared__ float wt[64][33];
  int b = blockIdx.z, w0 = blockIdx.x * 64, h0 = blockIdx.y * 64;
  int tid = threadIdx.x, tx = tid & 15, ty = tid >> 4;
  float acc[4][4] = {};
  for (int c0 = 0; c0 < 128; c0 += 32) {
    __syncthreads();
#pragma unroll
    for (int i = 0; i < 8; i++) {
      int f = i * 256 + tid, c = f >> 6, wl = f & 63;
      xt[c][wl] = inp[(b * 128 + c0 + c) * 512 + w0 + wl];
    }
#pragma unroll
    for (int i = 0; i < 8; i++) {
      int f = i * 256 + tid, h = f >> 5, c = f & 31;
      wt[h][c] = ew[(h0 + h) * 128 + c0 + c];
    }
    __syncthreads();
#pragma unroll
    for (int c = 0; c < 32; c++) {
      float xv[4], wv[4];
#pragma unroll
      for (int q = 0; q < 4; q++) xv[q] = xt[c][ty * 4 + q];
#pragma unroll
      for (int p = 0; p < 4; p++) wv[p] = wt[tx * 4 + p][c];
#pragma unroll
      for (int q = 0; q < 4; q++)
#pragma unroll
        for (int p = 0; p < 4; p++) acc[q][p] += xv[q] * wv[p];
    }
  }
#pragma unroll
  for (int q = 0; q < 4; q++) {
    int w = w0 + ty * 4 + q;
#pragma unroll
    for (int p = 0; p < 4; p++) {
      int h = h0 + tx * 4 + p;
      float v = acc[q][p] + eb[h];
      x0f[(b * 512 + w) * 256 + h] = f16b(v);
      if (w >= 510) out[(b * 256 + h) * 2 + (w - 510)] = v;  // x[0] tail
    }
  }
}

// ig[b,w,o] = sum_j sum_{i,k} xpad_j[b,w-1+k,i] * cw[off+j][o,i,k] + biases
__global__ __launch_bounds__(256) void conv_kernel(
    const unsigned short* __restrict__ xf, const unsigned* __restrict__ cwp,
    const float* __restrict__ cb, const float* __restrict__ hidden,
    unsigned short* __restrict__ igf, int l, int off) {
  __shared__ __align__(16) unsigned xs[65][20];    // [pad-col][dw16], stride 20
  __shared__ __align__(16) unsigned wsm[2][16][66];// [k][dw16][o], pad 66
  int b = blockIdx.z, w0 = blockIdx.x * 64, o0 = blockIdx.y * 64;
  int tid = threadIdx.x, tx = tid & 15, ty = tid >> 4;
  float acc[4][4] = {};
  int nl = l + 1;
  for (int j = 0; j < nl; j++) {
    const unsigned* xj = (const unsigned*)(xf + j * 4194304 + b * 512 * 256);
    const unsigned* cwj = cwp + (off + j) * 262144;
    for (int c0 = 0; c0 < 256; c0 += 32) {
      int d0 = c0 >> 1;
      __syncthreads();
#pragma unroll
      for (int i = 0; i < 5; i++) {
        int f = i * 256 + tid;
        if (f < 1040) {
          int col = f >> 4, dw = f & 15;
          int w = w0 - 1 + col;
          unsigned v;
          if (w >= 0) {
            v = xj[w * 128 + d0 + dw];
          } else {  // left pad: hidden[j][b][i][1]
            const float* hp = hidden + ((j * 32 + b) * 256 + 2 * (d0 + dw)) * 2 + 1;
            v = (unsigned)f16b(hp[0]) | ((unsigned)f16b(hp[2]) << 16);
          }
          xs[col][dw] = v;
        }
      }
#pragma unroll
      for (int i = 0; i < 8; i++) {
        int f = i * 256 + tid;
        int oo = f >> 5, k = (f >> 4) & 1, dw = f & 15;
        wsm[k][dw][oo] = cwj[(o0 + oo) * 256 + k * 128 + d0 + dw];
      }
      __syncthreads();
#pragma unroll
      for (int g = 0; g < 4; g++) {
        uint4 xv[5];
#pragma unroll
        for (int q = 0; q < 5; q++)
          xv[q] = *(const uint4*)&xs[ty * 4 + q][g * 4];
#pragma unroll
        for (int p = 0; p < 4; p++) {
          unsigned wv0[4], wv1[4];
#pragma unroll
          for (int r = 0; r < 4; r++) {
            wv0[r] = wsm[0][g * 4 + r][tx * 4 + p];
            wv1[r] = wsm[1][g * 4 + r][tx * 4 + p];
          }
#pragma unroll
          for (int q = 0; q < 4; q++) {
            float a = acc[q][p];
            a = fdot2(wv0[0], xv[q].x, a);
            a = fdot2(wv0[1], xv[q].y, a);
            a = fdot2(wv0[2], xv[q].z, a);
            a = fdot2(wv0[3], xv[q].w, a);
            a = fdot2(wv1[0], xv[q + 1].x, a);
            a = fdot2(wv1[1], xv[q + 1].y, a);
            a = fdot2(wv1[2], xv[q + 1].z, a);
            a = fdot2(wv1[3], xv[q + 1].w, a);
            acc[q][p] = a;
          }
        }
      }
    }
  }
#pragma unroll
  for (int p = 0; p < 4; p++) {
    int o = o0 + tx * 4 + p;
    float bias = 0.f;
    for (int j = 0; j < nl; j++) bias += cb[(off + j) * 1024 + o];
#pragma unroll
    for (int q = 0; q < 4; q++) {
      int w = w0 + ty * 4 + q;
      igf[(b * 512 + w) * 1024 + o] = f16b(acc[q][p] + bias);
    }
  }
}

// One WG per batch; 512 threads; lane (s=tid&3, u=tid>>2) computes 8 partial
// row-dots over 1/4 of hx, butterfly-reduced via DPP quad_perm adds.
// 1 barrier/step. Weights: 192 dw/thread pinned VGPRs + 64 dw/thread LDS.
__global__ __launch_bounds__(512)
__attribute__((amdgpu_waves_per_eu(2, 2)))
void rec_kernel(const _Float16* __restrict__ igf, const unsigned* __restrict__ rwp_l,
                const float* __restrict__ rb, const float* __restrict__ aw,
                const float* __restrict__ hidden, const float* __restrict__ context,
                int l, unsigned short* __restrict__ xnext, float* __restrict__ out) {
  __shared__ __align__(16) uint4 w_lds4[16 * 512];          // 128 KB
  // quarter s at elem offset s*72 (144B) -> each quarter on its own bank quad
  __shared__ __align__(16) unsigned short hx_buf[2][288];
  __shared__ float red[2][8];  // double-buffered attn partials
  int b = blockIdx.x, tid = threadIdx.x;
  int s = tid & 3, u = tid >> 2, lane = tid & 63, wid = tid >> 6;
  int hh = s & 1;
  int u2 = u + 128 * hh;                 // this lane's unit
  int hxi = (u2 >> 6) * 72 + (u2 & 63);  // swizzled store index for u2

  // 192 weight dwords -> pinned VGPRs
  unsigned wv[192];
#pragma unroll
  for (int d = 0; d < 192; d++) wv[d] = rwp_l[d * 512 + tid];
#pragma unroll
  for (int d = 0; d < 192; d++) asm volatile("" : "+v"(wv[d]));

  // 64 weight dwords -> LDS (conflict-free b128)
  {
    const uint4* g16 = (const uint4*)(rwp_l + 98304);
#pragma unroll
    for (int c = 0; c < 16; c++) w_lds4[c * 512 + tid] = g16[c * 512 + tid];
  }

  float rb0 = rb[u2], rb1 = rb[256 + u2], rb2 = rb[512 + u2], rb3 = rb[768 + u2];
  float awj = aw[u2];
  float cx = context[((l * 32 + b) * 256 + u2) * 2 + 1];
  if (tid < 256)
    hx_buf[1][(tid >> 6) * 72 + (tid & 63)] =
        f16b(hidden[(((l + 1) * 32 + b) * 256 + tid) * 2 + 1]);
  float h_prev = 0.f;
  __syncthreads();

  const _Float16* igb = igf + (b * 512) * 1024 + u2;

  for (int t = 0; t < 512; t++) {
    int cur = t & 1, prv = cur ^ 1;
    // ig prefetch (consumed after butterfly, ~1000 cyc later)
    const _Float16* ip = igb + t * 1024;
    float ig0 = (float)ip[0], ig1 = (float)ip[256];
    float ig2 = (float)ip[512], ig3 = (float)ip[768];
    // m = a_(t-1): deferred gating scalar (dot(w, a*h) = a*dot(w,h))
    float m_ = 1.0f;
    if (t) {
      const float* rp = red[prv];
      m_ = sigm(((rp[0] + rp[1]) + (rp[2] + rp[3])) +
                ((rp[4] + rp[5]) + (rp[6] + rp[7])));
    }

    float acc[8] = {};
    const uint4* hq = (const uint4*)(&hx_buf[prv][s * 72]);
#pragma unroll
    for (int q = 0; q < 6; q++) {
      uint4 h = hq[q];
#pragma unroll
      for (int rl = 0; rl < 8; rl++) {
        acc[rl] = fdot2(wv[rl * 24 + q * 4 + 0], h.x, acc[rl]);
        acc[rl] = fdot2(wv[rl * 24 + q * 4 + 1], h.y, acc[rl]);
        acc[rl] = fdot2(wv[rl * 24 + q * 4 + 2], h.z, acc[rl]);
        acc[rl] = fdot2(wv[rl * 24 + q * 4 + 3], h.w, acc[rl]);
      }
    }
#pragma unroll
    for (int q = 6; q < 8; q++) {
      uint4 h = hq[q];
#pragma unroll
      for (int rl = 0; rl < 8; rl++) {
        uint4 lw = w_lds4[(rl * 2 + (q - 6)) * 512 + tid];
        acc[rl] = fdot2(lw.x, h.x, acc[rl]);
        acc[rl] = fdot2(lw.y, h.y, acc[rl]);
        acc[rl] = fdot2(lw.z, h.z, acc[rl]);
        acc[rl] = fdot2(lw.w, h.w, acc[rl]);
      }
    }
    // butterfly over s (xor 1, then 2) via DPP quad_perm adds (VALU pipe,
    // replaces 16 ds_bpermute). Same pair/group order as shfl version ->
    // bit-identical sums on all 4 lanes.
#pragma unroll
    for (int rl = 0; rl < 8; rl++) acc[rl] = dpp_xadd<0xB1>(acc[rl]);
#pragma unroll
    for (int rl = 0; rl < 8; rl++) acc[rl] = dpp_xadd<0x4E>(acc[rl]);

    // this lane's 4 gates (rows g*256 + u2 <-> acc[g*2+hh])
    float di = hh ? acc[1] : acc[0];
    float df = hh ? acc[3] : acc[2];
    float dc = hh ? acc[5] : acc[4];
    float do_ = hh ? acc[7] : acc[6];
    float g_i = ig0 + rb0 + m_ * di;
    float g_f = ig1 + rb1 + m_ * df;
    float g_c = ig2 + rb2 + m_ * dc;
    float g_o = ig3 + rb3 + m_ * do_;
    cx = sigm(g_f) * cx + sigm(g_i) * tanh_(g_c);
    float h_raw = sigm(g_o) * tanh_(cx);

    // attention partial (mask the s=2,3 duplicate copies)
    float part = (s < 2) ? h_raw * awj : 0.f;
#pragma unroll
    for (int sh = 32; sh > 0; sh >>= 1) part += __shfl_xor(part, sh);
    if (lane == 0) red[cur][wid] = part;

    if (s < 2) {
      hx_buf[cur][hxi] = f16b(h_raw);  // store RAW h; gating deferred
      if (t) {
        float hg = h_prev * m_;  // gated h of step t-1
        xnext[(b * 512 + (t - 1)) * 256 + u2] = f16b(hg);
        if (t == 511)
          out[(((l + 1) * 32 + b) * 256 + u2) * 2 + 0] = hg;  // x tail w=510
      }
      if (t >= 510)
        out[65536 + ((l * 32 + b) * 256 + u2) * 2 + (t - 510)] = cx;  // nc tail
    }
    if (tid == 0 && t) out[114688 + (l * 32 + b) * 511 + (t - 1)] = m_;  // attn
    h_prev = h_raw;
    __syncthreads();
  }
  // flush last step (ungated)
  if (s < 2) {
    xnext[(b * 512 + 511) * 256 + u2] = f16b(h_prev);
    out[(((l + 1) * 32 + b) * 256 + u2) * 2 + 1] = h_prev;  // x tail w=511
  }
}

extern "C" void kernel_launch(void* const* d_in, const int* in_sizes, int n_in,
                              void* d_out, int out_size, void* d_ws,
                              size_t ws_size, hipStream_t stream) {
  const float* input  = (const float*)d_in[0];
  const float* hidden = (const float*)d_in[1];
  const float* context= (const float*)d_in[2];
  const float* emb_w  = (const float*)d_in[3];
  const float* emb_b  = (const float*)d_in[4];
  const float* conv_w = (const float*)d_in[5];
  const float* conv_b = (const float*)d_in[6];
  const float* rec_w  = (const float*)d_in[7];
  const float* rec_b  = (const float*)d_in[8];
  const float* attn_w = (const float*)d_in[9];
  float* out = (float*)d_out;

  char* ws = (char*)d_ws;
  unsigned short* xf16 = (unsigned short*)ws;                    // 4 x 4,194,304 f16 = 32 MB
  _Float16* igf = (_Float16*)(ws + 33554432);                    // 16,777,216 f16 = 32 MB
  unsigned* rwp = (unsigned*)(ws + 67108864);                    // 1.5 MB
  unsigned* cwp = (unsigned*)(ws + 68681728);                    // 6 MB

  hipLaunchKernelGGL(prep_rw, dim3(1536), dim3(256), 0, stream, rec_w, rwp);
  hipLaunchKernelGGL(prep_cw, dim3(6144), dim3(256), 0, stream, conv_w, cwp);
  hipLaunchKernelGGL(emb_kernel, dim3(8, 4, 32), dim3(256), 0, stream,
                     input, emb_w, emb_b, xf16, out);
  int off = 0;
  for (int l = 0; l < 3; l++) {
    hipLaunchKernelGGL(conv_kernel, dim3(8, 16, 32), dim3(256), 0, stream,
                       xf16, cwp, conv_b, hidden, (unsigned short*)igf, l, off);
    hipLaunchKernelGGL(rec_kernel, dim3(32), dim3(512), 0, stream,
                       igf, rwp + l * 131072, rec_b + l * 1024,
                       attn_w + l * 256, hidden, context, l,
                       xf16 + (l + 1) * 4194304, out);
    off += l + 1;
  }
}

// Round 13
// 4143.633 us; speedup vs baseline: 1.0667x; 1.0270x over previous
//
#include <hip/hip_runtime.h>

// ---------------------------------------------------------------------------
// Encoder_conv: emb (1x1 conv) -> 3x { multi-tap K=2 convs summed -> LSTM scan
// with per-step attention gating }.
// B=32, W=512, H=256, 4H=1024, NINP=128, K=2, NLAYERS=3.
//
// Round 18: rec/emb/preps = R11 verbatim (best verified: total 4255us, rec
// 1066us, absmax 0.00390625). NEW: conv_kernel DS-pipe diet (~950us of the
// total is conv at <20% of dot2 peak; per-chunk model: 128 scalar b32 weight
// reads = 742 of ~1110 DS cycles vs 1024 VALU -> DS co-binding):
//  - output remap o = o0 + tx + 16p (oo&7 spans 8 values across the wave;
//    also makes the igf epilogue stores 16-contiguous).
//  - wsm -> [64][32] with XOR-swizzled 16B chunks (chunk c at pos c^(oo&7)):
//    weight reads become 2x ds_read_b128 per (g,p) at 2-way (free) banks;
//    128 b32 -> 32 b128 per chunk. Same weights, same fdot2 order ->
//    bit-identical.
//  - xs staging vectorized: 1040 b32 -> 260 b128 (global dwordx4 + b128
//    writes, 2-way banks); left-pad path builds the uint4 from hidden.
// Failed lines stay closed: batch-pair (r6), AGPR weights (r8), L2 weight
// stream (r10), attn-tail rework (r12/r13), fused conv/rec overlap (r14-16).
// ---------------------------------------------------------------------------

typedef _Float16 h2 __attribute__((ext_vector_type(2)));

static __device__ __forceinline__ float fdot2(unsigned a, unsigned b, float c) {
#if __has_builtin(__builtin_amdgcn_fdot2)
  return __builtin_amdgcn_fdot2(__builtin_bit_cast(h2, a),
                                __builtin_bit_cast(h2, b), c, false);
#else
  h2 x = __builtin_bit_cast(h2, a), y = __builtin_bit_cast(h2, b);
  return c + (float)x[0] * (float)y[0] + (float)x[1] * (float)y[1];
#endif
}

static __device__ __forceinline__ unsigned short f16b(float v) {
  _Float16 h = (_Float16)v;
  return __builtin_bit_cast(unsigned short, h);
}

static __device__ __forceinline__ float sigm(float x) {
  return 1.0f / (1.0f + __expf(-x));
}
static __device__ __forceinline__ float tanh_(float x) {
  return 1.0f - 2.0f / (1.0f + __expf(2.0f * x));
}

// x + (x from lane^delta) within each quad, via DPP quad_perm.
// xor1 = quad_perm(1,0,3,2) = 0xB1 ; xor2 = quad_perm(2,3,0,1) = 0x4E.
template <int CTRL>
static __device__ __forceinline__ float dpp_xadd(float x) {
  int y = __builtin_amdgcn_mov_dpp(__builtin_bit_cast(int, x), CTRL, 0xF, 0xF,
                                   true);
  return x + __builtin_bit_cast(float, y);
}

// Packs rec_w per layer (131072 dwords/layer) for the butterfly rec kernel.
// Thread tid: s=tid&3, u=tid>>2; rows row=(rl>>1)*256+(rl&1)*128+u (rl=0..7);
// K-pairs j in [0,32) at global pair cp = s*32+j:
//   j<24      -> VGPR: off = (rl*24+j)*512 + tid
//   j=24..31  -> LDS : c = rl*2+((j-24)>>2), k=(j-24)&3
//                      off = 98304 + c*2048 + tid*4 + k
__global__ __launch_bounds__(256) void prep_rw(const float* __restrict__ rw,
                                               unsigned* __restrict__ rwp) {
  int idx = blockIdx.x * 256 + threadIdx.x;
  if (idx >= 3 * 131072) return;
  int l = idx / 131072, pos = idx % 131072;
  int tid, rl, j;
  if (pos < 98304) {
    int d = pos >> 9;
    tid = pos & 511;
    rl = d / 24;
    j = d % 24;
  } else {
    int p = pos - 98304;
    int c = p >> 11, rem = p & 2047;
    tid = rem >> 2;
    int k = rem & 3;
    rl = c >> 1;
    j = 24 + (c & 1) * 4 + k;
  }
  int s = tid & 3, u = tid >> 2;
  int row = (rl >> 1) * 256 + (rl & 1) * 128 + u;
  int cp = s * 32 + j;
  const float* src = rw + (l * 1024 + row) * 256 + 2 * cp;
  rwp[idx] = (unsigned)f16b(src[0]) | ((unsigned)f16b(src[1]) << 16);
}

// cwp[jj][o][k][d] = pack(f16(conv_w[jj][o][2d][k]), f16(conv_w[jj][o][2d+1][k]))
__global__ __launch_bounds__(256) void prep_cw(const float* __restrict__ cw,
                                               unsigned* __restrict__ cwp) {
  int idx = blockIdx.x * 256 + threadIdx.x;
  if (idx >= 6 * 1024 * 2 * 128) return;
  int d = idx & 127, k = (idx >> 7) & 1, o = (idx >> 8) & 1023, jj = idx >> 18;
  const float* src = cw + ((jj * 1024 + o) * 256 + 2 * d) * 2 + k;
  unsigned v = (unsigned)f16b(src[0]) | ((unsigned)f16b(src[2]) << 16);
  cwp[idx] = v;
}

// x0[b,w,h] = sum_c emb_w[h,c]*input[b,c,w] + emb_b[h]; store f16 + out tail.
__global__ __launch_bounds__(256) void emb_kernel(
    const float* __restrict__ inp, const float* __restrict__ ew,
    const float* __restrict__ eb, unsigned short* __restrict__ x0f,
    float* __restrict__ out) {
  __shared__ float xt[32][65];
  __shared__ float wt[64][33];
  int b = blockIdx.z, w0 = blockIdx.x * 64, h0 = blockIdx.y * 64;
  int tid = threadIdx.x, tx = tid & 15, ty = tid >> 4;
  float acc[4][4] = {};
  for (int c0 = 0; c0 < 128; c0 += 32) {
    __syncthreads();
#pragma unroll
    for (int i = 0; i < 8; i++) {
      int f = i * 256 + tid, c = f >> 6, wl = f & 63;
      xt[c][wl] = inp[(b * 128 + c0 + c) * 512 + w0 + wl];
    }
#pragma unroll
    for (int i = 0; i < 8; i++) {
      int f = i * 256 + tid, h = f >> 5, c = f & 31;
      wt[h][c] = ew[(h0 + h) * 128 + c0 + c];
    }
    __syncthreads();
#pragma unroll
    for (int c = 0; c < 32; c++) {
      float xv[4], wv[4];
#pragma unroll
      for (int q = 0; q < 4; q++) xv[q] = xt[c][ty * 4 + q];
#pragma unroll
      for (int p = 0; p < 4; p++) wv[p] = wt[tx * 4 + p][c];
#pragma unroll
      for (int q = 0; q < 4; q++)
#pragma unroll
        for (int p = 0; p < 4; p++) acc[q][p] += xv[q] * wv[p];
    }
  }
#pragma unroll
  for (int q = 0; q < 4; q++) {
    int w = w0 + ty * 4 + q;
#pragma unroll
    for (int p = 0; p < 4; p++) {
      int h = h0 + tx * 4 + p;
      float v = acc[q][p] + eb[h];
      x0f[(b * 512 + w) * 256 + h] = f16b(v);
      if (w >= 510) out[(b * 256 + h) * 2 + (w - 510)] = v;  // x[0] tail
    }
  }
}

// ig[b,w,o] = sum_j sum_{i,k} xpad_j[b,w-1+k,i] * cw[off+j][o,i,k] + biases
// Thread (tx=tid&15, ty=tid>>4) owns outputs o = o0 + tx + 16p (p 0..3) at
// w = w0 + ty*4 + q (q 0..3). Weights live in wsm[64][32] with the 16B chunk
// c (= k*4 + dw/4) of row oo stored at position c ^ (oo&7)  -> b128 reads at
// 2-way (free) bank conflicts. Same weights, same fdot2 order as before.
__global__ __launch_bounds__(256) void conv_kernel(
    const unsigned short* __restrict__ xf, const unsigned* __restrict__ cwp,
    const float* __restrict__ cb, const float* __restrict__ hidden,
    unsigned short* __restrict__ igf, int l, int off) {
  __shared__ __align__(16) unsigned xs[65][20];  // [pad-col][dw16], stride 20
  __shared__ __align__(16) unsigned wsm[64 * 32];  // [oo][chunk^swz][j]
  int b = blockIdx.z, w0 = blockIdx.x * 64, o0 = blockIdx.y * 64;
  int tid = threadIdx.x, tx = tid & 15, ty = tid >> 4;
  float acc[4][4] = {};
  int nl = l + 1;
  for (int j = 0; j < nl; j++) {
    const unsigned* xj = (const unsigned*)(xf + j * 4194304 + b * 512 * 256);
    const unsigned* cwj = cwp + (off + j) * 262144;
    for (int c0 = 0; c0 < 256; c0 += 32) {
      int d0 = c0 >> 1;
      __syncthreads();
      // xs staging: 260 uint4 (was 1040 b32). Same values.
#pragma unroll
      for (int i = 0; i < 2; i++) {
        int f = i * 256 + tid;
        if (f < 260) {
          int col = f >> 2, q4 = f & 3;
          int w = w0 - 1 + col;
          uint4 v;
          if (w >= 0) {
            v = *(const uint4*)&xj[w * 128 + d0 + 4 * q4];
          } else {  // left pad: hidden[j][b][i][1], dwords 4q4..4q4+3
            const float* hp =
                hidden + ((j * 32 + b) * 256 + 2 * (d0 + 4 * q4)) * 2 + 1;
            v.x = (unsigned)f16b(hp[0]) | ((unsigned)f16b(hp[2]) << 16);
            v.y = (unsigned)f16b(hp[4]) | ((unsigned)f16b(hp[6]) << 16);
            v.z = (unsigned)f16b(hp[8]) | ((unsigned)f16b(hp[10]) << 16);
            v.w = (unsigned)f16b(hp[12]) | ((unsigned)f16b(hp[14]) << 16);
          }
          *(uint4*)&xs[col][4 * q4] = v;
        }
      }
      // weight staging with XOR swizzle (b32 writes, 2-way banks)
#pragma unroll
      for (int i = 0; i < 8; i++) {
        int f = i * 256 + tid;
        int oo = f >> 5, k = (f >> 4) & 1, dw = f & 15;
        int c = k * 4 + (dw >> 2);
        wsm[oo * 32 + ((c ^ (oo & 7)) << 2) + (dw & 3)] =
            cwj[(o0 + oo) * 256 + k * 128 + d0 + dw];
      }
      __syncthreads();
      const uint4* wsm4 = (const uint4*)wsm;
#pragma unroll
      for (int g = 0; g < 4; g++) {
        uint4 xv[5];
#pragma unroll
        for (int q = 0; q < 5; q++)
          xv[q] = *(const uint4*)&xs[ty * 4 + q][g * 4];
#pragma unroll
        for (int p = 0; p < 4; p++) {
          int oo = tx + 16 * p, sw = oo & 7;
          uint4 lw0 = wsm4[oo * 8 + (g ^ sw)];        // k=0, dw g*4..g*4+3
          uint4 lw1 = wsm4[oo * 8 + ((4 + g) ^ sw)];  // k=1, dw g*4..g*4+3
#pragma unroll
          for (int q = 0; q < 4; q++) {
            float a = acc[q][p];
            a = fdot2(lw0.x, xv[q].x, a);
            a = fdot2(lw0.y, xv[q].y, a);
            a = fdot2(lw0.z, xv[q].z, a);
            a = fdot2(lw0.w, xv[q].w, a);
            a = fdot2(lw1.x, xv[q + 1].x, a);
            a = fdot2(lw1.y, xv[q + 1].y, a);
            a = fdot2(lw1.z, xv[q + 1].z, a);
            a = fdot2(lw1.w, xv[q + 1].w, a);
            acc[q][p] = a;
          }
        }
      }
    }
  }
#pragma unroll
  for (int p = 0; p < 4; p++) {
    int o = o0 + tx + 16 * p;
    float bias = 0.f;
    for (int j = 0; j < nl; j++) bias += cb[(off + j) * 1024 + o];
#pragma unroll
    for (int q = 0; q < 4; q++) {
      int w = w0 + ty * 4 + q;
      igf[(b * 512 + w) * 1024 + o] = f16b(acc[q][p] + bias);
    }
  }
}

// One WG per batch; 512 threads; lane (s=tid&3, u=tid>>2) computes 8 partial
// row-dots over 1/4 of hx, butterfly-reduced via DPP quad_perm adds.
// 1 barrier/step. Weights: 192 dw/thread pinned VGPRs + 64 dw/thread LDS.
__global__ __launch_bounds__(512)
__attribute__((amdgpu_waves_per_eu(2, 2)))
void rec_kernel(const _Float16* __restrict__ igf, const unsigned* __restrict__ rwp_l,
                const float* __restrict__ rb, const float* __restrict__ aw,
                const float* __restrict__ hidden, const float* __restrict__ context,
                int l, unsigned short* __restrict__ xnext, float* __restrict__ out) {
  __shared__ __align__(16) uint4 w_lds4[16 * 512];          // 128 KB
  // quarter s at elem offset s*72 (144B) -> each quarter on its own bank quad
  __shared__ __align__(16) unsigned short hx_buf[2][288];
  __shared__ float red[2][8];  // double-buffered attn partials
  int b = blockIdx.x, tid = threadIdx.x;
  int s = tid & 3, u = tid >> 2, lane = tid & 63, wid = tid >> 6;
  int hh = s & 1;
  int u2 = u + 128 * hh;                 // this lane's unit
  int hxi = (u2 >> 6) * 72 + (u2 & 63);  // swizzled store index for u2

  // 192 weight dwords -> pinned VGPRs
  unsigned wv[192];
#pragma unroll
  for (int d = 0; d < 192; d++) wv[d] = rwp_l[d * 512 + tid];
#pragma unroll
  for (int d = 0; d < 192; d++) asm volatile("" : "+v"(wv[d]));

  // 64 weight dwords -> LDS (conflict-free b128)
  {
    const uint4* g16 = (const uint4*)(rwp_l + 98304);
#pragma unroll
    for (int c = 0; c < 16; c++) w_lds4[c * 512 + tid] = g16[c * 512 + tid];
  }

  float rb0 = rb[u2], rb1 = rb[256 + u2], rb2 = rb[512 + u2], rb3 = rb[768 + u2];
  float awj = aw[u2];
  float cx = context[((l * 32 + b) * 256 + u2) * 2 + 1];
  if (tid < 256)
    hx_buf[1][(tid >> 6) * 72 + (tid & 63)] =
        f16b(hidden[(((l + 1) * 32 + b) * 256 + tid) * 2 + 1]);
  float h_prev = 0.f;
  __syncthreads();

  const _Float16* igb = igf + (b * 512) * 1024 + u2;

  for (int t = 0; t < 512; t++) {
    int cur = t & 1, prv = cur ^ 1;
    // ig prefetch (consumed after butterfly, ~1000 cyc later)
    const _Float16* ip = igb + t * 1024;
    float ig0 = (float)ip[0], ig1 = (float)ip[256];
    float ig2 = (float)ip[512], ig3 = (float)ip[768];
    // m = a_(t-1): deferred gating scalar (dot(w, a*h) = a*dot(w,h))
    float m_ = 1.0f;
    if (t) {
      const float* rp = red[prv];
      m_ = sigm(((rp[0] + rp[1]) + (rp[2] + rp[3])) +
                ((rp[4] + rp[5]) + (rp[6] + rp[7])));
    }

    float acc[8] = {};
    const uint4* hq = (const uint4*)(&hx_buf[prv][s * 72]);
#pragma unroll
    for (int q = 0; q < 6; q++) {
      uint4 h = hq[q];
#pragma unroll
      for (int rl = 0; rl < 8; rl++) {
        acc[rl] = fdot2(wv[rl * 24 + q * 4 + 0], h.x, acc[rl]);
        acc[rl] = fdot2(wv[rl * 24 + q * 4 + 1], h.y, acc[rl]);
        acc[rl] = fdot2(wv[rl * 24 + q * 4 + 2], h.z, acc[rl]);
        acc[rl] = fdot2(wv[rl * 24 + q * 4 + 3], h.w, acc[rl]);
      }
    }
#pragma unroll
    for (int q = 6; q < 8; q++) {
      uint4 h = hq[q];
#pragma unroll
      for (int rl = 0; rl < 8; rl++) {
        uint4 lw = w_lds4[(rl * 2 + (q - 6)) * 512 + tid];
        acc[rl] = fdot2(lw.x, h.x, acc[rl]);
        acc[rl] = fdot2(lw.y, h.y, acc[rl]);
        acc[rl] = fdot2(lw.z, h.z, acc[rl]);
        acc[rl] = fdot2(lw.w, h.w, acc[rl]);
      }
    }
    // butterfly over s (xor 1, then 2) via DPP quad_perm adds (VALU pipe,
    // replaces 16 ds_bpermute). Same pair/group order as shfl version ->
    // bit-identical sums on all 4 lanes.
#pragma unroll
    for (int rl = 0; rl < 8; rl++) acc[rl] = dpp_xadd<0xB1>(acc[rl]);
#pragma unroll
    for (int rl = 0; rl < 8; rl++) acc[rl] = dpp_xadd<0x4E>(acc[rl]);

    // this lane's 4 gates (rows g*256 + u2 <-> acc[g*2+hh])
    float di = hh ? acc[1] : acc[0];
    float df = hh ? acc[3] : acc[2];
    float dc = hh ? acc[5] : acc[4];
    float do_ = hh ? acc[7] : acc[6];
    float g_i = ig0 + rb0 + m_ * di;
    float g_f = ig1 + rb1 + m_ * df;
    float g_c = ig2 + rb2 + m_ * dc;
    float g_o = ig3 + rb3 + m_ * do_;
    cx = sigm(g_f) * cx + sigm(g_i) * tanh_(g_c);
    float h_raw = sigm(g_o) * tanh_(cx);

    // attention partial (mask the s=2,3 duplicate copies)
    float part = (s < 2) ? h_raw * awj : 0.f;
#pragma unroll
    for (int sh = 32; sh > 0; sh >>= 1) part += __shfl_xor(part, sh);
    if (lane == 0) red[cur][wid] = part;

    if (s < 2) {
      hx_buf[cur][hxi] = f16b(h_raw);  // store RAW h; gating deferred
      if (t) {
        float hg = h_prev * m_;  // gated h of step t-1
        xnext[(b * 512 + (t - 1)) * 256 + u2] = f16b(hg);
        if (t == 511)
          out[(((l + 1) * 32 + b) * 256 + u2) * 2 + 0] = hg;  // x tail w=510
      }
      if (t >= 510)
        out[65536 + ((l * 32 + b) * 256 + u2) * 2 + (t - 510)] = cx;  // nc tail
    }
    if (tid == 0 && t) out[114688 + (l * 32 + b) * 511 + (t - 1)] = m_;  // attn
    h_prev = h_raw;
    __syncthreads();
  }
  // flush last step (ungated)
  if (s < 2) {
    xnext[(b * 512 + 511) * 256 + u2] = f16b(h_prev);
    out[(((l + 1) * 32 + b) * 256 + u2) * 2 + 1] = h_prev;  // x tail w=511
  }
}

extern "C" void kernel_launch(void* const* d_in, const int* in_sizes, int n_in,
                              void* d_out, int out_size, void* d_ws,
                              size_t ws_size, hipStream_t stream) {
  const float* input  = (const float*)d_in[0];
  const float* hidden = (const float*)d_in[1];
  const float* context= (const float*)d_in[2];
  const float* emb_w  = (const float*)d_in[3];
  const float* emb_b  = (const float*)d_in[4];
  const float* conv_w = (const float*)d_in[5];
  const float* conv_b = (const float*)d_in[6];
  const float* rec_w  = (const float*)d_in[7];
  const float* rec_b  = (const float*)d_in[8];
  const float* attn_w = (const float*)d_in[9];
  float* out = (float*)d_out;

  char* ws = (char*)d_ws;
  unsigned short* xf16 = (unsigned short*)ws;                    // 4 x 4,194,304 f16 = 32 MB
  _Float16* igf = (_Float16*)(ws + 33554432);                    // 16,777,216 f16 = 32 MB
  unsigned* rwp = (unsigned*)(ws + 67108864);                    // 1.5 MB
  unsigned* cwp = (unsigned*)(ws + 68681728);                    // 6 MB

  hipLaunchKernelGGL(prep_rw, dim3(1536), dim3(256), 0, stream, rec_w, rwp);
  hipLaunchKernelGGL(prep_cw, dim3(6144), dim3(256), 0, stream, conv_w, cwp);
  hipLaunchKernelGGL(emb_kernel, dim3(8, 4, 32), dim3(256), 0, stream,
                     input, emb_w, emb_b, xf16, out);
  int off = 0;
  for (int l = 0; l < 3; l++) {
    hipLaunchKernelGGL(conv_kernel, dim3(8, 16, 32), dim3(256), 0, stream,
                       xf16, cwp, conv_b, hidden, (unsigned short*)igf, l, off);
    hipLaunchKernelGGL(rec_kernel, dim3(32), dim3(512), 0, stream,
                       igf, rwp + l * 131072, rec_b + l * 1024,
                       attn_w + l * 256, hidden, context, l,
                       xf16 + (l + 1) * 4194304, out);
    off += l + 1;
  }
}

// Round 14
// 4084.775 us; speedup vs baseline: 1.0821x; 1.0144x over previous
//
#include <hip/hip_runtime.h>

// ---------------------------------------------------------------------------
// Encoder_conv: emb (1x1 conv) -> 3x { multi-tap K=2 convs summed -> LSTM scan
// with per-step attention gating }.
// B=32, W=512, H=256, 4H=1024, NINP=128, K=2, NLAYERS=3.
//
// Round 19: rec/emb/preps unchanged (R11; total 4143us verified with R18
// conv). conv retile 4o x 4w -> 4o x 8w per thread (w-tile 128, grid
// 4x16x32): weight b128 reads amortize over 8 w's -> DS-per-output 52 -> 34
// b128 (-35%); per-g wave ledger 17 b128 (204cyc) vs 256 fdot2 (512cyc) =
// VALU-bound. New xs col-stride-8 would be 4-way bank conflict (160 dwords
// = 0 mod 32); fixed with R18's XOR-chunk swizzle on xs (chunk ^= (col>>3)&3)
// -> conflict-free. Per-output fdot2 order (j -> c0 -> g -> k0,k1) untouched
// -> bit-identical. Closed lines: batch-pair(r6), AGPR(r8), L2-stream(r10),
// attn-tail(r12/13), fused overlap(r14-16).
// ---------------------------------------------------------------------------

typedef _Float16 h2 __attribute__((ext_vector_type(2)));

static __device__ __forceinline__ float fdot2(unsigned a, unsigned b, float c) {
#if __has_builtin(__builtin_amdgcn_fdot2)
  return __builtin_amdgcn_fdot2(__builtin_bit_cast(h2, a),
                                __builtin_bit_cast(h2, b), c, false);
#else
  h2 x = __builtin_bit_cast(h2, a), y = __builtin_bit_cast(h2, b);
  return c + (float)x[0] * (float)y[0] + (float)x[1] * (float)y[1];
#endif
}

static __device__ __forceinline__ unsigned short f16b(float v) {
  _Float16 h = (_Float16)v;
  return __builtin_bit_cast(unsigned short, h);
}

static __device__ __forceinline__ float sigm(float x) {
  return 1.0f / (1.0f + __expf(-x));
}
static __device__ __forceinline__ float tanh_(float x) {
  return 1.0f - 2.0f / (1.0f + __expf(2.0f * x));
}

// x + (x from lane^delta) within each quad, via DPP quad_perm.
// xor1 = quad_perm(1,0,3,2) = 0xB1 ; xor2 = quad_perm(2,3,0,1) = 0x4E.
template <int CTRL>
static __device__ __forceinline__ float dpp_xadd(float x) {
  int y = __builtin_amdgcn_mov_dpp(__builtin_bit_cast(int, x), CTRL, 0xF, 0xF,
                                   true);
  return x + __builtin_bit_cast(float, y);
}

// Packs rec_w per layer (131072 dwords/layer) for the butterfly rec kernel.
// Thread tid: s=tid&3, u=tid>>2; rows row=(rl>>1)*256+(rl&1)*128+u (rl=0..7);
// K-pairs j in [0,32) at global pair cp = s*32+j:
//   j<24      -> VGPR: off = (rl*24+j)*512 + tid
//   j=24..31  -> LDS : c = rl*2+((j-24)>>2), k=(j-24)&3
//                      off = 98304 + c*2048 + tid*4 + k
__global__ __launch_bounds__(256) void prep_rw(const float* __restrict__ rw,
                                               unsigned* __restrict__ rwp) {
  int idx = blockIdx.x * 256 + threadIdx.x;
  if (idx >= 3 * 131072) return;
  int l = idx / 131072, pos = idx % 131072;
  int tid, rl, j;
  if (pos < 98304) {
    int d = pos >> 9;
    tid = pos & 511;
    rl = d / 24;
    j = d % 24;
  } else {
    int p = pos - 98304;
    int c = p >> 11, rem = p & 2047;
    tid = rem >> 2;
    int k = rem & 3;
    rl = c >> 1;
    j = 24 + (c & 1) * 4 + k;
  }
  int s = tid & 3, u = tid >> 2;
  int row = (rl >> 1) * 256 + (rl & 1) * 128 + u;
  int cp = s * 32 + j;
  const float* src = rw + (l * 1024 + row) * 256 + 2 * cp;
  rwp[idx] = (unsigned)f16b(src[0]) | ((unsigned)f16b(src[1]) << 16);
}

// cwp[jj][o][k][d] = pack(f16(conv_w[jj][o][2d][k]), f16(conv_w[jj][o][2d+1][k]))
__global__ __launch_bounds__(256) void prep_cw(const float* __restrict__ cw,
                                               unsigned* __restrict__ cwp) {
  int idx = blockIdx.x * 256 + threadIdx.x;
  if (idx >= 6 * 1024 * 2 * 128) return;
  int d = idx & 127, k = (idx >> 7) & 1, o = (idx >> 8) & 1023, jj = idx >> 18;
  const float* src = cw + ((jj * 1024 + o) * 256 + 2 * d) * 2 + k;
  unsigned v = (unsigned)f16b(src[0]) | ((unsigned)f16b(src[2]) << 16);
  cwp[idx] = v;
}

// x0[b,w,h] = sum_c emb_w[h,c]*input[b,c,w] + emb_b[h]; store f16 + out tail.
__global__ __launch_bounds__(256) void emb_kernel(
    const float* __restrict__ inp, const float* __restrict__ ew,
    const float* __restrict__ eb, unsigned short* __restrict__ x0f,
    float* __restrict__ out) {
  __shared__ float xt[32][65];
  __shared__ float wt[64][33];
  int b = blockIdx.z, w0 = blockIdx.x * 64, h0 = blockIdx.y * 64;
  int tid = threadIdx.x, tx = tid & 15, ty = tid >> 4;
  float acc[4][4] = {};
  for (int c0 = 0; c0 < 128; c0 += 32) {
    __syncthreads();
#pragma unroll
    for (int i = 0; i < 8; i++) {
      int f = i * 256 + tid, c = f >> 6, wl = f & 63;
      xt[c][wl] = inp[(b * 128 + c0 + c) * 512 + w0 + wl];
    }
#pragma unroll
    for (int i = 0; i < 8; i++) {
      int f = i * 256 + tid, h = f >> 5, c = f & 31;
      wt[h][c] = ew[(h0 + h) * 128 + c0 + c];
    }
    __syncthreads();
#pragma unroll
    for (int c = 0; c < 32; c++) {
      float xv[4], wv[4];
#pragma unroll
      for (int q = 0; q < 4; q++) xv[q] = xt[c][ty * 4 + q];
#pragma unroll
      for (int p = 0; p < 4; p++) wv[p] = wt[tx * 4 + p][c];
#pragma unroll
      for (int q = 0; q < 4; q++)
#pragma unroll
        for (int p = 0; p < 4; p++) acc[q][p] += xv[q] * wv[p];
    }
  }
#pragma unroll
  for (int q = 0; q < 4; q++) {
    int w = w0 + ty * 4 + q;
#pragma unroll
    for (int p = 0; p < 4; p++) {
      int h = h0 + tx * 4 + p;
      float v = acc[q][p] + eb[h];
      x0f[(b * 512 + w) * 256 + h] = f16b(v);
      if (w >= 510) out[(b * 256 + h) * 2 + (w - 510)] = v;  // x[0] tail
    }
  }
}

// ig[b,w,o] = sum_j sum_{i,k} xpad_j[b,w-1+k,i] * cw[off+j][o,i,k] + biases
// Thread (tx=tid&15, ty=tid>>4) owns o = o0 + tx + 16p (p 0..3) at
// w = w0 + ty*8 + q (q 0..7); w-tile 128. Weights in wsm[64][32], 16B chunk
// c stored at c ^ (oo&7) (R18). xs[129][20] with chunk g stored at
// g ^ ((col>>3)&3) -> col-stride-8 reads conflict-free. Same weights/inputs,
// same per-output fdot2 order -> bit-identical.
__global__ __launch_bounds__(256) void conv_kernel(
    const unsigned short* __restrict__ xf, const unsigned* __restrict__ cwp,
    const float* __restrict__ cb, const float* __restrict__ hidden,
    unsigned short* __restrict__ igf, int l, int off) {
  __shared__ __align__(16) unsigned xs[129 * 20];  // [pad-col][chunk^swz]
  __shared__ __align__(16) unsigned wsm[64 * 32];  // [oo][chunk^swz]
  int b = blockIdx.z, w0 = blockIdx.x * 128, o0 = blockIdx.y * 64;
  int tid = threadIdx.x, tx = tid & 15, ty = tid >> 4;
  float acc[8][4] = {};
  int nl = l + 1;
  for (int j = 0; j < nl; j++) {
    const unsigned* xj = (const unsigned*)(xf + j * 4194304 + b * 512 * 256);
    const unsigned* cwj = cwp + (off + j) * 262144;
    for (int c0 = 0; c0 < 256; c0 += 32) {
      int d0 = c0 >> 1;
      __syncthreads();
      // xs staging: 516 uint4 (129 pad-cols x 4 chunks), chunk-swizzled.
#pragma unroll
      for (int i = 0; i < 3; i++) {
        int f = i * 256 + tid;
        if (f < 516) {
          int col = f >> 2, q4 = f & 3;
          int w = w0 - 1 + col;
          uint4 v;
          if (w >= 0) {
            v = *(const uint4*)&xj[w * 128 + d0 + 4 * q4];
          } else {  // left pad: hidden[j][b][i][1], dwords 4q4..4q4+3
            const float* hp =
                hidden + ((j * 32 + b) * 256 + 2 * (d0 + 4 * q4)) * 2 + 1;
            v.x = (unsigned)f16b(hp[0]) | ((unsigned)f16b(hp[2]) << 16);
            v.y = (unsigned)f16b(hp[4]) | ((unsigned)f16b(hp[6]) << 16);
            v.z = (unsigned)f16b(hp[8]) | ((unsigned)f16b(hp[10]) << 16);
            v.w = (unsigned)f16b(hp[12]) | ((unsigned)f16b(hp[14]) << 16);
          }
          *(uint4*)&xs[col * 20 + 4 * (q4 ^ ((col >> 3) & 3))] = v;
        }
      }
      // weight staging with XOR swizzle (b32 writes, 2-way banks)
#pragma unroll
      for (int i = 0; i < 8; i++) {
        int f = i * 256 + tid;
        int oo = f >> 5, k = (f >> 4) & 1, dw = f & 15;
        int c = k * 4 + (dw >> 2);
        wsm[oo * 32 + ((c ^ (oo & 7)) << 2) + (dw & 3)] =
            cwj[(o0 + oo) * 256 + k * 128 + d0 + dw];
      }
      __syncthreads();
      const uint4* wsm4 = (const uint4*)wsm;
#pragma unroll
      for (int g = 0; g < 4; g++) {
        uint4 xv[9];
#pragma unroll
        for (int q = 0; q < 9; q++) {
          int col = ty * 8 + q;
          xv[q] = *(const uint4*)&xs[col * 20 + 4 * (g ^ ((col >> 3) & 3))];
        }
#pragma unroll
        for (int p = 0; p < 4; p++) {
          int oo = tx + 16 * p, sw = oo & 7;
          uint4 lw0 = wsm4[oo * 8 + (g ^ sw)];        // k=0, dw g*4..g*4+3
          uint4 lw1 = wsm4[oo * 8 + ((4 + g) ^ sw)];  // k=1, dw g*4..g*4+3
#pragma unroll
          for (int q = 0; q < 8; q++) {
            float a = acc[q][p];
            a = fdot2(lw0.x, xv[q].x, a);
            a = fdot2(lw0.y, xv[q].y, a);
            a = fdot2(lw0.z, xv[q].z, a);
            a = fdot2(lw0.w, xv[q].w, a);
            a = fdot2(lw1.x, xv[q + 1].x, a);
            a = fdot2(lw1.y, xv[q + 1].y, a);
            a = fdot2(lw1.z, xv[q + 1].z, a);
            a = fdot2(lw1.w, xv[q + 1].w, a);
            acc[q][p] = a;
          }
        }
      }
    }
  }
#pragma unroll
  for (int p = 0; p < 4; p++) {
    int o = o0 + tx + 16 * p;
    float bias = 0.f;
    for (int j = 0; j < nl; j++) bias += cb[(off + j) * 1024 + o];
#pragma unroll
    for (int q = 0; q < 8; q++) {
      int w = w0 + ty * 8 + q;
      igf[(b * 512 + w) * 1024 + o] = f16b(acc[q][p] + bias);
    }
  }
}

// One WG per batch; 512 threads; lane (s=tid&3, u=tid>>2) computes 8 partial
// row-dots over 1/4 of hx, butterfly-reduced via DPP quad_perm adds.
// 1 barrier/step. Weights: 192 dw/thread pinned VGPRs + 64 dw/thread LDS.
__global__ __launch_bounds__(512)
__attribute__((amdgpu_waves_per_eu(2, 2)))
void rec_kernel(const _Float16* __restrict__ igf, const unsigned* __restrict__ rwp_l,
                const float* __restrict__ rb, const float* __restrict__ aw,
                const float* __restrict__ hidden, const float* __restrict__ context,
                int l, unsigned short* __restrict__ xnext, float* __restrict__ out) {
  __shared__ __align__(16) uint4 w_lds4[16 * 512];          // 128 KB
  // quarter s at elem offset s*72 (144B) -> each quarter on its own bank quad
  __shared__ __align__(16) unsigned short hx_buf[2][288];
  __shared__ float red[2][8];  // double-buffered attn partials
  int b = blockIdx.x, tid = threadIdx.x;
  int s = tid & 3, u = tid >> 2, lane = tid & 63, wid = tid >> 6;
  int hh = s & 1;
  int u2 = u + 128 * hh;                 // this lane's unit
  int hxi = (u2 >> 6) * 72 + (u2 & 63);  // swizzled store index for u2

  // 192 weight dwords -> pinned VGPRs
  unsigned wv[192];
#pragma unroll
  for (int d = 0; d < 192; d++) wv[d] = rwp_l[d * 512 + tid];
#pragma unroll
  for (int d = 0; d < 192; d++) asm volatile("" : "+v"(wv[d]));

  // 64 weight dwords -> LDS (conflict-free b128)
  {
    const uint4* g16 = (const uint4*)(rwp_l + 98304);
#pragma unroll
    for (int c = 0; c < 16; c++) w_lds4[c * 512 + tid] = g16[c * 512 + tid];
  }

  float rb0 = rb[u2], rb1 = rb[256 + u2], rb2 = rb[512 + u2], rb3 = rb[768 + u2];
  float awj = aw[u2];
  float cx = context[((l * 32 + b) * 256 + u2) * 2 + 1];
  if (tid < 256)
    hx_buf[1][(tid >> 6) * 72 + (tid & 63)] =
        f16b(hidden[(((l + 1) * 32 + b) * 256 + tid) * 2 + 1]);
  float h_prev = 0.f;
  __syncthreads();

  const _Float16* igb = igf + (b * 512) * 1024 + u2;

  for (int t = 0; t < 512; t++) {
    int cur = t & 1, prv = cur ^ 1;
    // ig prefetch (consumed after butterfly, ~1000 cyc later)
    const _Float16* ip = igb + t * 1024;
    float ig0 = (float)ip[0], ig1 = (float)ip[256];
    float ig2 = (float)ip[512], ig3 = (float)ip[768];
    // m = a_(t-1): deferred gating scalar (dot(w, a*h) = a*dot(w,h))
    float m_ = 1.0f;
    if (t) {
      const float* rp = red[prv];
      m_ = sigm(((rp[0] + rp[1]) + (rp[2] + rp[3])) +
                ((rp[4] + rp[5]) + (rp[6] + rp[7])));
    }

    float acc[8] = {};
    const uint4* hq = (const uint4*)(&hx_buf[prv][s * 72]);
#pragma unroll
    for (int q = 0; q < 6; q++) {
      uint4 h = hq[q];
#pragma unroll
      for (int rl = 0; rl < 8; rl++) {
        acc[rl] = fdot2(wv[rl * 24 + q * 4 + 0], h.x, acc[rl]);
        acc[rl] = fdot2(wv[rl * 24 + q * 4 + 1], h.y, acc[rl]);
        acc[rl] = fdot2(wv[rl * 24 + q * 4 + 2], h.z, acc[rl]);
        acc[rl] = fdot2(wv[rl * 24 + q * 4 + 3], h.w, acc[rl]);
      }
    }
#pragma unroll
    for (int q = 6; q < 8; q++) {
      uint4 h = hq[q];
#pragma unroll
      for (int rl = 0; rl < 8; rl++) {
        uint4 lw = w_lds4[(rl * 2 + (q - 6)) * 512 + tid];
        acc[rl] = fdot2(lw.x, h.x, acc[rl]);
        acc[rl] = fdot2(lw.y, h.y, acc[rl]);
        acc[rl] = fdot2(lw.z, h.z, acc[rl]);
        acc[rl] = fdot2(lw.w, h.w, acc[rl]);
      }
    }
    // butterfly over s (xor 1, then 2) via DPP quad_perm adds (VALU pipe,
    // replaces 16 ds_bpermute). Same pair/group order as shfl version ->
    // bit-identical sums on all 4 lanes.
#pragma unroll
    for (int rl = 0; rl < 8; rl++) acc[rl] = dpp_xadd<0xB1>(acc[rl]);
#pragma unroll
    for (int rl = 0; rl < 8; rl++) acc[rl] = dpp_xadd<0x4E>(acc[rl]);

    // this lane's 4 gates (rows g*256 + u2 <-> acc[g*2+hh])
    float di = hh ? acc[1] : acc[0];
    float df = hh ? acc[3] : acc[2];
    float dc = hh ? acc[5] : acc[4];
    float do_ = hh ? acc[7] : acc[6];
    float g_i = ig0 + rb0 + m_ * di;
    float g_f = ig1 + rb1 + m_ * df;
    float g_c = ig2 + rb2 + m_ * dc;
    float g_o = ig3 + rb3 + m_ * do_;
    cx = sigm(g_f) * cx + sigm(g_i) * tanh_(g_c);
    float h_raw = sigm(g_o) * tanh_(cx);

    // attention partial (mask the s=2,3 duplicate copies)
    float part = (s < 2) ? h_raw * awj : 0.f;
#pragma unroll
    for (int sh = 32; sh > 0; sh >>= 1) part += __shfl_xor(part, sh);
    if (lane == 0) red[cur][wid] = part;

    if (s < 2) {
      hx_buf[cur][hxi] = f16b(h_raw);  // store RAW h; gating deferred
      if (t) {
        float hg = h_prev * m_;  // gated h of step t-1
        xnext[(b * 512 + (t - 1)) * 256 + u2] = f16b(hg);
        if (t == 511)
          out[(((l + 1) * 32 + b) * 256 + u2) * 2 + 0] = hg;  // x tail w=510
      }
      if (t >= 510)
        out[65536 + ((l * 32 + b) * 256 + u2) * 2 + (t - 510)] = cx;  // nc tail
    }
    if (tid == 0 && t) out[114688 + (l * 32 + b) * 511 + (t - 1)] = m_;  // attn
    h_prev = h_raw;
    __syncthreads();
  }
  // flush last step (ungated)
  if (s < 2) {
    xnext[(b * 512 + 511) * 256 + u2] = f16b(h_prev);
    out[(((l + 1) * 32 + b) * 256 + u2) * 2 + 1] = h_prev;  // x tail w=511
  }
}

extern "C" void kernel_launch(void* const* d_in, const int* in_sizes, int n_in,
                              void* d_out, int out_size, void* d_ws,
                              size_t ws_size, hipStream_t stream) {
  const float* input  = (const float*)d_in[0];
  const float* hidden = (const float*)d_in[1];
  const float* context= (const float*)d_in[2];
  const float* emb_w  = (const float*)d_in[3];
  const float* emb_b  = (const float*)d_in[4];
  const float* conv_w = (const float*)d_in[5];
  const float* conv_b = (const float*)d_in[6];
  const float* rec_w  = (const float*)d_in[7];
  const float* rec_b  = (const float*)d_in[8];
  const float* attn_w = (const float*)d_in[9];
  float* out = (float*)d_out;

  char* ws = (char*)d_ws;
  unsigned short* xf16 = (unsigned short*)ws;                    // 4 x 4,194,304 f16 = 32 MB
  _Float16* igf = (_Float16*)(ws + 33554432);                    // 16,777,216 f16 = 32 MB
  unsigned* rwp = (unsigned*)(ws + 67108864);                    // 1.5 MB
  unsigned* cwp = (unsigned*)(ws + 68681728);                    // 6 MB

  hipLaunchKernelGGL(prep_rw, dim3(1536), dim3(256), 0, stream, rec_w, rwp);
  hipLaunchKernelGGL(prep_cw, dim3(6144), dim3(256), 0, stream, conv_w, cwp);
  hipLaunchKernelGGL(emb_kernel, dim3(8, 4, 32), dim3(256), 0, stream,
                     input, emb_w, emb_b, xf16, out);
  int off = 0;
  for (int l = 0; l < 3; l++) {
    hipLaunchKernelGGL(conv_kernel, dim3(4, 16, 32), dim3(256), 0, stream,
                       xf16, cwp, conv_b, hidden, (unsigned short*)igf, l, off);
    hipLaunchKernelGGL(rec_kernel, dim3(32), dim3(512), 0, stream,
                       igf, rwp + l * 131072, rec_b + l * 1024,
                       attn_w + l * 256, hidden, context, l,
                       xf16 + (l + 1) * 4194304, out);
    off += l + 1;
  }
}